// Round 5
// baseline (122.592 us; speedup 1.0000x reference)
//
#include <hip/hip_runtime.h>

// DiscriminativeLoss: data [32, 512, 1024] f32 (D-planar), labels [512,1024] i32 in [0,16)
// out: scalar f32 loss.
//
// Lessons so far:
//  - LDS float atomicAdd (ds_add_f32) ~300 cyc/wave-instr on gfx950 -> never in hot loop.
//  - Harness re-poison (268 MB ws fill ~42us + d_in restore ~22us) is inside the timed
//    window: ~70us fixed. 2 kernels, no ws memset, no global atomics in pass 1.
//  - LDS accumulator layout acc[k*256 + tid]: bank = tid%32 regardless of label ->
//    deterministic 2-way (free) instead of label-dependent ~5-way conflicts.
//
// ws float layout:
//   partials[(k*32 + d)*32 + chunk] : [0, 16384)
//   cpart[k*32 + chunk]             : [16384, 16896)

constexpr int KC = 16;
constexpr int DD = 32;
constexpr int NN = 512 * 1024;
constexpr int N4 = NN / 4;                        // 131072 float4 groups per d-plane
constexpr int N2 = NN / 2;                        // 262144 float2 groups per d-plane
constexpr int CHUNKS = 32;
constexpr int GROUPS_PER_CHUNK = N4 / CHUNKS;     // 4096
constexpr int K1_ITERS = GROUPS_PER_CHUNK / 256;  // 16

constexpr int WS_P  = 0;
constexpr int WS_CP = 16384;

__global__ __launch_bounds__(256) void kA_sums(const float4* __restrict__ data4,
                                               const int4* __restrict__ lab4,
                                               float* __restrict__ ws,
                                               float* __restrict__ out) {
    const int tid = threadIdx.x;
    const int chunk = blockIdx.x;
    const int d = blockIdx.y;
    const bool doCnt = (d == 0);

    if (chunk == 0 && d == 0 && tid == 0) out[0] = 0.f;  // kB atomicAdds on top

    // acc[k*256 + tid]: per-thread column, bank = tid%32 independent of k -> conflict-free.
    __shared__ float acc[KC * 256];
    __shared__ float cnt[KC * 256];
#pragma unroll
    for (int k = 0; k < KC; ++k) acc[k * 256 + tid] = 0.f;
    if (doCnt) {
#pragma unroll
        for (int k = 0; k < KC; ++k) cnt[k * 256 + tid] = 0.f;
    }
    __syncthreads();   // not strictly needed (columns private) but cheap

    const float4* dplane = data4 + (size_t)d * N4;
    int g = chunk * GROUPS_PER_CHUNK + tid;

    // 1-deep register prefetch: overlap next loads with current LDS RMW chain.
    float4 v = dplane[g];
    int4 lb = lab4[g];
    for (int it = 0; it < K1_ITERS; ++it) {
        float4 vn;
        int4 lbn;
        if (it + 1 < K1_ITERS) {
            vn = dplane[g + 256];
            lbn = lab4[g + 256];
        }
        acc[lb.x * 256 + tid] += v.x;
        acc[lb.y * 256 + tid] += v.y;
        acc[lb.z * 256 + tid] += v.z;
        acc[lb.w * 256 + tid] += v.w;
        if (doCnt) {
            cnt[lb.x * 256 + tid] += 1.f;
            cnt[lb.y * 256 + tid] += 1.f;
            cnt[lb.z * 256 + tid] += 1.f;
            cnt[lb.w * 256 + tid] += 1.f;
        }
        v = vn;
        lb = lbn;
        g += 256;
    }
    __syncthreads();

    // Epilogue: thread t -> cluster k = t>>4, segment seg = t&15 (16 elements each).
    const int k = tid >> 4, seg = tid & 15;
    float s = 0.f;
#pragma unroll
    for (int i = 0; i < 16; ++i) s += acc[k * 256 + seg * 16 + i];
#pragma unroll
    for (int off = 8; off > 0; off >>= 1) s += __shfl_down(s, off, 16);
    if (seg == 0) ws[WS_P + (k * DD + d) * CHUNKS + chunk] = s;   // plain store
    if (doCnt) {
        float c = 0.f;
#pragma unroll
        for (int i = 0; i < 16; ++i) c += cnt[k * 256 + seg * 16 + i];
#pragma unroll
        for (int off = 8; off > 0; off >>= 1) c += __shfl_down(c, off, 16);
        if (seg == 0) ws[WS_CP + k * CHUNKS + chunk] = c;         // plain store
    }
}

__global__ __launch_bounds__(256) void kB_var(const float2* __restrict__ data2,
                                              const int2* __restrict__ lab2,
                                              const float* __restrict__ ws,
                                              float* __restrict__ out) {
    __shared__ float csum[KC * 33];      // stride 33 spreads banks for the ct2 build
    __shared__ float ccnt[KC];
    __shared__ float ct2[DD * 32];       // centers_t duplicated (k and k+16 identical)
    const int tid = threadIdx.x;

    // Every block redundantly reduces the chunk-partials (66 KB, L2/L3-resident).
    {
        int idx = tid;                   // (k*32 + d), two per thread
        const float* p = ws + WS_P + idx * CHUNKS;
        float s = 0.f;
#pragma unroll
        for (int c = 0; c < CHUNKS; ++c) s += p[c];
        csum[(idx >> 5) * 33 + (idx & 31)] = s;
        idx = tid + 256;
        p = ws + WS_P + idx * CHUNKS;
        s = 0.f;
#pragma unroll
        for (int c = 0; c < CHUNKS; ++c) s += p[c];
        csum[(idx >> 5) * 33 + (idx & 31)] = s;
    }
    if (tid < KC) {
        const float* p = ws + WS_CP + tid * CHUNKS;
        float c = 0.f;
#pragma unroll
        for (int i = 0; i < CHUNKS; ++i) c += p[i];
        ccnt[tid] = c;
    }
    __syncthreads();

    for (int idx = tid; idx < KC * DD; idx += 256) {
        const int k = idx >> 5, d = idx & 31;
        const float c = csum[k * 33 + d] / ccnt[k];
        ct2[d * 32 + k] = c;
        ct2[d * 32 + 16 + k] = c;
    }
    __syncthreads();

    // Block 0 only: pairwise distance term + reg term.
    if (blockIdx.x == 0) {
        const int i = tid >> 4, j = tid & 15;
        float val;
        if (i != j) {
            float sq = 0.f;
#pragma unroll
            for (int d = 0; d < DD; ++d) {
                const float df = ct2[d * 32 + i] - ct2[d * 32 + j];
                sq += df * df;
            }
            const float pd = sqrtf(sq);
            const float t = fmaxf(3.0f - pd, 0.f);            // 2*DELTA_DIST
            val = t * t * (1.0f / (KC * (KC - 1)));
        } else {
            float s2 = 0.f;
#pragma unroll
            for (int d = 0; d < DD; ++d) s2 += ct2[d * 32 + i] * ct2[d * 32 + i];
            val = sqrtf(s2) * (0.001f / KC);                   // reg term
        }
        __shared__ float red[256];
        red[tid] = val;
        __syncthreads();
        for (int off = 128; off > 0; off >>= 1) {
            if (tid < off) red[tid] += red[tid + off];
            __syncthreads();
        }
        if (tid == 0) atomicAdd(out, red[0]);
        __syncthreads();
    }

    // Pass 2: one float2 group (2 points) per thread; 1024 blocks x 256 = N2.
    const int g = blockIdx.x * 256 + tid;
    const int2 lb = lab2[g];
    const int dup = (tid & 32) >> 1;     // lanes 32-63 read the +16 duplicate
    const int o0 = lb.x + dup, o1 = lb.y + dup;

    float s0 = 0.f, s1 = 0.f;
#pragma unroll 8
    for (int d = 0; d < DD; ++d) {
        const float2 v = data2[(size_t)d * N2 + g];
        const float* ctd = ct2 + d * 32;
        const float d0 = ctd[o0] - v.x; s0 += d0 * d0;
        const float d1 = ctd[o1] - v.y; s1 += d1 * d1;
    }
    const float h0 = fmaxf(sqrtf(s0) - 0.5f, 0.f);
    const float h1 = fmaxf(sqrtf(s1) - 0.5f, 0.f);
    float lsum = h0 * h0 + h1 * h1;

#pragma unroll
    for (int off = 32; off > 0; off >>= 1) lsum += __shfl_down(lsum, off);
    __shared__ float wred[4];
    if ((tid & 63) == 0) wred[tid >> 6] = lsum;
    __syncthreads();
    if (tid == 0) {
        const float s = wred[0] + wred[1] + wred[2] + wred[3];
        atomicAdd(out, s * (1.0f / KC));
    }
}

extern "C" void kernel_launch(void* const* d_in, const int* in_sizes, int n_in,
                              void* d_out, int out_size, void* d_ws, size_t ws_size,
                              hipStream_t stream) {
    const float4* data4 = (const float4*)d_in[0];
    const int4* lab4 = (const int4*)d_in[1];
    float* out = (float*)d_out;
    float* ws = (float*)d_ws;

    kA_sums<<<dim3(CHUNKS, DD), 256, 0, stream>>>(data4, lab4, ws, out);
    kB_var<<<1024, 256, 0, stream>>>((const float2*)d_in[0], (const int2*)d_in[1], ws, out);
}